// Round 1
// baseline (45.843 us; speedup 1.0000x reference)
//
#include <hip/hip_runtime.h>

#define NODES 14
#define IN_F 24
#define HID1 32
#define HID2 64
#define OUT_F 24
#define SLOPE 0.2f

__global__ __launch_bounds__(64) void gnn_fused(
    const float* __restrict__ x, const float* __restrict__ y,
    const float* __restrict__ W1, const float* __restrict__ a_src1,
    const float* __restrict__ a_dst1, const float* __restrict__ b1,
    const float* __restrict__ W2, const float* __restrict__ a_src2,
    const float* __restrict__ a_dst2, const float* __restrict__ b2,
    const float* __restrict__ Wf1, const float* __restrict__ bf1,
    const float* __restrict__ Wf2, const float* __restrict__ bf2,
    float* __restrict__ out, int ngraphs)
{
  const int g = blockIdx.x;
  const int tid = threadIdx.x;

  __shared__ float xs[NODES * IN_F];         // 336
  __shared__ float xh1[NODES * 64];          // 896  (col = h*32+f)
  __shared__ float als[NODES * 2];
  __shared__ float ald[NODES * 2];
  __shared__ float watt[NODES * NODES * 2];  // w[i][j][h]
  __shared__ float h1s[NODES * HID1];        // 448
  __shared__ float xh2[NODES * 128];         // 1792 (col = h*64+f)
  __shared__ float h2s[NODES * HID2];        // 896
  __shared__ float hhs[NODES * 8];           // 112

  // ---- stage x ----
  for (int i = tid; i < NODES * IN_F; i += 64)
    xs[i] = x[(size_t)g * (NODES * IN_F) + i];
  __syncthreads();

  // ---- layer1 GEMM: xh1[n][tid] ----
  {
    float w[IN_F];
#pragma unroll
    for (int k = 0; k < IN_F; ++k) w[k] = W1[k * 64 + tid];
#pragma unroll
    for (int n = 0; n < NODES; ++n) {
      float acc = 0.f;
#pragma unroll
      for (int k = 0; k < IN_F; ++k) acc += xs[n * IN_F + k] * w[k];
      xh1[n * 64 + tid] = acc;
    }
  }
  __syncthreads();

  // ---- layer1 attention logits (28 lanes: (n,h)) ----
  if (tid < NODES * 2) {
    int n = tid >> 1, h = tid & 1;
    float s = 0.f, d = 0.f;
#pragma unroll
    for (int f = 0; f < HID1; ++f) {
      float v = xh1[n * 64 + h * HID1 + f];
      s += v * a_src1[h * HID1 + f];
      d += v * a_dst1[h * HID1 + f];
    }
    als[tid] = s; ald[tid] = d;
  }
  __syncthreads();

  // ---- layer1 softmax weights (28 lanes: (j,h)) ----
  if (tid < NODES * 2) {
    int j = tid >> 1, h = tid & 1;
    float ad = ald[j * 2 + h];
    float a[NODES]; float m = -1e30f;
#pragma unroll
    for (int i = 0; i < NODES; ++i) {
      float v = als[i * 2 + h] + ad;
      v = v > 0.f ? v : SLOPE * v;
      a[i] = v; m = fmaxf(m, v);
    }
    float den = 0.f;
#pragma unroll
    for (int i = 0; i < NODES; ++i) { a[i] = __expf(a[i] - m); den += a[i]; }
    float r = 1.f / den;
#pragma unroll
    for (int i = 0; i < NODES; ++i) watt[(i * NODES + j) * 2 + h] = a[i] * r;
  }
  __syncthreads();

  // ---- layer1 aggregate + head-mean + bias + ELU -> h1s ----
  {
    int h = tid >> 5, f = tid & 31;
    float bb = b1[f];
#pragma unroll
    for (int n = 0; n < NODES; ++n) {
      float o = 0.f;
#pragma unroll
      for (int i = 0; i < NODES; ++i)
        o += watt[(i * NODES + n) * 2 + h] * xh1[i * 64 + tid];
      float other = __shfl_xor(o, 32);
      if (h == 0) {
        float v = 0.5f * (o + other) + bb;
        h1s[n * HID1 + f] = v > 0.f ? v : expm1f(v);
      }
    }
  }
  __syncthreads();

  // ---- layer2 GEMM: xh2[n][c], c = tid and tid+64 ----
  {
    float w[HID1];
#pragma unroll
    for (int half = 0; half < 2; ++half) {
      int c = tid + half * 64;
#pragma unroll
      for (int k = 0; k < HID1; ++k) w[k] = W2[k * 128 + c];
#pragma unroll
      for (int n = 0; n < NODES; ++n) {
        float acc = 0.f;
#pragma unroll
        for (int k = 0; k < HID1; ++k) acc += h1s[n * HID1 + k] * w[k];
        xh2[n * 128 + c] = acc;
      }
    }
  }
  __syncthreads();

  // ---- layer2 attention logits ----
  if (tid < NODES * 2) {
    int n = tid >> 1, h = tid & 1;
    float s = 0.f, d = 0.f;
#pragma unroll
    for (int f = 0; f < HID2; ++f) {
      float v = xh2[n * 128 + h * HID2 + f];
      s += v * a_src2[h * HID2 + f];
      d += v * a_dst2[h * HID2 + f];
    }
    als[tid] = s; ald[tid] = d;
  }
  __syncthreads();

  // ---- layer2 softmax weights ----
  if (tid < NODES * 2) {
    int j = tid >> 1, h = tid & 1;
    float ad = ald[j * 2 + h];
    float a[NODES]; float m = -1e30f;
#pragma unroll
    for (int i = 0; i < NODES; ++i) {
      float v = als[i * 2 + h] + ad;
      v = v > 0.f ? v : SLOPE * v;
      a[i] = v; m = fmaxf(m, v);
    }
    float den = 0.f;
#pragma unroll
    for (int i = 0; i < NODES; ++i) { a[i] = __expf(a[i] - m); den += a[i]; }
    float r = 1.f / den;
#pragma unroll
    for (int i = 0; i < NODES; ++i) watt[(i * NODES + j) * 2 + h] = a[i] * r;
  }
  __syncthreads();

  // ---- layer2 aggregate + head-mean + bias -> h2s (no activation) ----
  {
    float bb = b2[tid];
#pragma unroll
    for (int n = 0; n < NODES; ++n) {
      float o0 = 0.f, o1 = 0.f;
#pragma unroll
      for (int i = 0; i < NODES; ++i) {
        float w0 = watt[(i * NODES + n) * 2 + 0];
        float w1 = watt[(i * NODES + n) * 2 + 1];
        o0 += w0 * xh2[i * 128 + tid];
        o1 += w1 * xh2[i * 128 + 64 + tid];
      }
      h2s[n * HID2 + tid] = 0.5f * (o0 + o1) + bb;
    }
  }
  __syncthreads();

  // ---- per-node-index MLP layer 1: hh = relu(h2 @ Wf1[k] + bf1[k]) ----
  for (int idx = tid; idx < NODES * 8; idx += 64) {
    int k = idx >> 3, e = idx & 7;
    float acc = bf1[k * 8 + e];
#pragma unroll
    for (int f = 0; f < HID2; ++f)
      acc += h2s[k * HID2 + f] * Wf1[(k * HID2 + f) * 8 + e];
    hhs[idx] = fmaxf(acc, 0.f);
  }
  __syncthreads();

  // ---- per-node-index MLP layer 2: pred = sigmoid(hh @ Wf2[k] + bf2[k]) ----
  for (int idx = tid; idx < NODES * OUT_F; idx += 64) {
    int k = idx / OUT_F, o = idx % OUT_F;
    float acc = bf2[k * OUT_F + o];
#pragma unroll
    for (int e = 0; e < 8; ++e)
      acc += hhs[k * 8 + e] * Wf2[(k * 8 + e) * OUT_F + o];
    float p = 1.f / (1.f + __expf(-acc));
    out[(size_t)k * ngraphs * OUT_F + (size_t)g * OUT_F + o] = p;
  }

  // ---- second output: yg = y.reshape(B,14,24) == y flat copy ----
  {
    const size_t ybase = (size_t)g * (NODES * OUT_F);
    const size_t obase = (size_t)NODES * ngraphs * OUT_F;
    for (int idx = tid; idx < NODES * OUT_F; idx += 64)
      out[obase + ybase + idx] = y[ybase + idx];
  }
}

extern "C" void kernel_launch(void* const* d_in, const int* in_sizes, int n_in,
                              void* d_out, int out_size, void* d_ws, size_t ws_size,
                              hipStream_t stream) {
  const float* x      = (const float*)d_in[0];
  const float* y      = (const float*)d_in[1];
  // d_in[2] = edge_index, d_in[3] = batch : structure is fixed, unused
  const float* W1     = (const float*)d_in[4];
  const float* a_src1 = (const float*)d_in[5];
  const float* a_dst1 = (const float*)d_in[6];
  const float* b1     = (const float*)d_in[7];
  const float* W2     = (const float*)d_in[8];
  const float* a_src2 = (const float*)d_in[9];
  const float* a_dst2 = (const float*)d_in[10];
  const float* b2     = (const float*)d_in[11];
  const float* Wf1    = (const float*)d_in[12];
  const float* bf1    = (const float*)d_in[13];
  const float* Wf2    = (const float*)d_in[14];
  const float* bf2    = (const float*)d_in[15];
  float* out = (float*)d_out;

  int nnodes  = in_sizes[0] / IN_F;
  int ngraphs = nnodes / NODES;

  hipLaunchKernelGGL(gnn_fused, dim3(ngraphs), dim3(64), 0, stream,
                     x, y, W1, a_src1, a_dst1, b1, W2, a_src2, a_dst2, b2,
                     Wf1, bf1, Wf2, bf2, out, ngraphs);
}

// Round 2
// 36.013 us; speedup vs baseline: 1.2730x; 1.2730x over previous
//
#include <hip/hip_runtime.h>

#define NODES 14
#define IN_F 24
#define HID1 32
#define HID2 64
#define OUT_F 24
#define SLOPE 0.2f

__global__ __launch_bounds__(64) void gnn_fused(
    const float* __restrict__ x, const float* __restrict__ y,
    const float* __restrict__ W1, const float* __restrict__ a_src1,
    const float* __restrict__ a_dst1, const float* __restrict__ b1,
    const float* __restrict__ W2, const float* __restrict__ a_src2,
    const float* __restrict__ a_dst2, const float* __restrict__ b2,
    const float* __restrict__ Wf1, const float* __restrict__ bf1,
    const float* __restrict__ Wf2, const float* __restrict__ bf2,
    float* __restrict__ out, int ngraphs)
{
  const int g = blockIdx.x;
  const int tid = threadIdx.x;

  __shared__ __align__(16) float xs[NODES * IN_F];   // 336
  __shared__ float als[NODES * 2];
  __shared__ float ald[NODES * 2];
  __shared__ float watt[NODES * NODES * 2];          // [i][j][h] = i*28 + j*2 + h
  __shared__ __align__(16) float h1s[NODES * HID1];  // 448
  __shared__ __align__(16) float h2s[NODES * 68];    // padded stride 68
  __shared__ float hhs[NODES * 8];                   // 112

  // ---- independent y-copy first (hide store latency under compute) ----
  {
    const float4* y4 = (const float4*)(y + (size_t)g * (NODES * OUT_F));
    float4* o4 = (float4*)(out + (size_t)NODES * ngraphs * OUT_F
                               + (size_t)g * (NODES * OUT_F));
#pragma unroll
    for (int idx = tid; idx < (NODES * OUT_F) / 4; idx += 64)
      o4[idx] = y4[idx];
  }

  // ---- stage x (float4) ----
  {
    const float4* x4 = (const float4*)(x + (size_t)g * (NODES * IN_F));
    float4* s4 = (float4*)xs;
#pragma unroll
    for (int idx = tid; idx < (NODES * IN_F) / 4; idx += 64)
      s4[idx] = x4[idx];
  }
  __syncthreads();

  // ---- layer1: GEMM column-in-register + in-wave logit reduction ----
  float xcol[NODES];  // xh1[n][tid]
  {
    float w[IN_F];
#pragma unroll
    for (int k = 0; k < IN_F; ++k) w[k] = W1[k * 64 + tid];
    const float asrc = a_src1[tid];  // a_src1 flat [2*32] == col index tid
    const float adst = a_dst1[tid];
    const int h = tid >> 5, f5 = tid & 31;
#pragma unroll
    for (int n = 0; n < NODES; ++n) {
      float acc = 0.f;
#pragma unroll
      for (int k4 = 0; k4 < IN_F / 4; ++k4) {
        const float4 xv = *(const float4*)&xs[n * IN_F + k4 * 4];
        acc += xv.x * w[k4 * 4 + 0] + xv.y * w[k4 * 4 + 1]
             + xv.z * w[k4 * 4 + 2] + xv.w * w[k4 * 4 + 3];
      }
      xcol[n] = acc;
      float s = acc * asrc, d = acc * adst;
#pragma unroll
      for (int off = 1; off < 32; off <<= 1) {
        s += __shfl_xor(s, off);
        d += __shfl_xor(d, off);
      }
      if (f5 == 0) { als[n * 2 + h] = s; ald[n * 2 + h] = d; }
    }
  }
  __syncthreads();

  // ---- layer1 softmax weights (28 lanes: (j,h)) ----
  if (tid < NODES * 2) {
    const int j = tid >> 1, h = tid & 1;
    const float ad = ald[j * 2 + h];
    float a[NODES]; float m = -1e30f;
#pragma unroll
    for (int i = 0; i < NODES; ++i) {
      float v = als[i * 2 + h] + ad;
      v = v > 0.f ? v : SLOPE * v;
      a[i] = v; m = fmaxf(m, v);
    }
    float den = 0.f;
#pragma unroll
    for (int i = 0; i < NODES; ++i) { a[i] = __expf(a[i] - m); den += a[i]; }
    const float r = 1.f / den;
#pragma unroll
    for (int i = 0; i < NODES; ++i) watt[i * 28 + tid] = a[i] * r;
  }
  __syncthreads();

  // ---- layer1 aggregate (from registers) + head-mean + bias + ELU ----
  {
    const int h = tid >> 5, f5 = tid & 31;
    const float bb = b1[f5];
#pragma unroll
    for (int n = 0; n < NODES; ++n) {
      float o = 0.f;
#pragma unroll
      for (int i = 0; i < NODES; ++i)
        o += watt[i * 28 + n * 2 + h] * xcol[i];
      const float other = __shfl_xor(o, 32);
      if (h == 0) {
        const float v = 0.5f * (o + other) + bb;
        h1s[n * HID1 + f5] = v > 0.f ? v : expm1f(v);
      }
    }
  }
  __syncthreads();

  // ---- layer2: two column halves, sequential (reuse weight regs) ----
  float x2c0[NODES], x2c1[NODES];
  {
    float w2[HID1];
    // half 0: col = tid (head 0)
#pragma unroll
    for (int k = 0; k < HID1; ++k) w2[k] = W2[k * 128 + tid];
    {
      const float as2 = a_src2[tid], ad2 = a_dst2[tid];
#pragma unroll
      for (int n = 0; n < NODES; ++n) {
        float acc = 0.f;
#pragma unroll
        for (int k4 = 0; k4 < HID1 / 4; ++k4) {
          const float4 hv = *(const float4*)&h1s[n * HID1 + k4 * 4];
          acc += hv.x * w2[k4 * 4 + 0] + hv.y * w2[k4 * 4 + 1]
               + hv.z * w2[k4 * 4 + 2] + hv.w * w2[k4 * 4 + 3];
        }
        x2c0[n] = acc;
        float s = acc * as2, d = acc * ad2;
#pragma unroll
        for (int off = 1; off < 64; off <<= 1) {
          s += __shfl_xor(s, off);
          d += __shfl_xor(d, off);
        }
        if (tid == 0) { als[n * 2 + 0] = s; ald[n * 2 + 0] = d; }
      }
    }
    // half 1: col = 64 + tid (head 1)
#pragma unroll
    for (int k = 0; k < HID1; ++k) w2[k] = W2[k * 128 + 64 + tid];
    {
      const float as2 = a_src2[64 + tid], ad2 = a_dst2[64 + tid];
#pragma unroll
      for (int n = 0; n < NODES; ++n) {
        float acc = 0.f;
#pragma unroll
        for (int k4 = 0; k4 < HID1 / 4; ++k4) {
          const float4 hv = *(const float4*)&h1s[n * HID1 + k4 * 4];
          acc += hv.x * w2[k4 * 4 + 0] + hv.y * w2[k4 * 4 + 1]
               + hv.z * w2[k4 * 4 + 2] + hv.w * w2[k4 * 4 + 3];
        }
        x2c1[n] = acc;
        float s = acc * as2, d = acc * ad2;
#pragma unroll
        for (int off = 1; off < 64; off <<= 1) {
          s += __shfl_xor(s, off);
          d += __shfl_xor(d, off);
        }
        if (tid == 0) { als[n * 2 + 1] = s; ald[n * 2 + 1] = d; }
      }
    }
  }
  __syncthreads();

  // ---- layer2 softmax weights ----
  if (tid < NODES * 2) {
    const int j = tid >> 1, h = tid & 1;
    const float ad = ald[j * 2 + h];
    float a[NODES]; float m = -1e30f;
#pragma unroll
    for (int i = 0; i < NODES; ++i) {
      float v = als[i * 2 + h] + ad;
      v = v > 0.f ? v : SLOPE * v;
      a[i] = v; m = fmaxf(m, v);
    }
    float den = 0.f;
#pragma unroll
    for (int i = 0; i < NODES; ++i) { a[i] = __expf(a[i] - m); den += a[i]; }
    const float r = 1.f / den;
#pragma unroll
    for (int i = 0; i < NODES; ++i) watt[i * 28 + tid] = a[i] * r;
  }
  __syncthreads();

  // ---- layer2 aggregate (registers) + head-mean + bias -> h2s ----
  {
    const float bb = b2[tid];
#pragma unroll
    for (int n = 0; n < NODES; ++n) {
      float o0 = 0.f, o1 = 0.f;
#pragma unroll
      for (int i = 0; i < NODES; ++i) {
        const float2 wv = *(const float2*)&watt[i * 28 + n * 2];
        o0 += wv.x * x2c0[i];
        o1 += wv.y * x2c1[i];
      }
      h2s[n * 68 + tid] = 0.5f * (o0 + o1) + bb;
    }
  }
  __syncthreads();

  // ---- per-node MLP layer 1: hh = relu(h2 @ Wf1[k] + bf1[k]) ----
  for (int idx = tid; idx < NODES * 8; idx += 64) {
    const int k = idx >> 3, e = idx & 7;
    float acc = bf1[k * 8 + e];
#pragma unroll
    for (int f = 0; f < HID2; ++f)
      acc += h2s[k * 68 + f] * Wf1[(k * HID2 + f) * 8 + e];
    hhs[idx] = fmaxf(acc, 0.f);
  }
  __syncthreads();

  // ---- per-node MLP layer 2: pred = sigmoid(hh @ Wf2[k] + bf2[k]) ----
  for (int idx = tid; idx < NODES * OUT_F; idx += 64) {
    const int k = idx / OUT_F, o = idx % OUT_F;
    float acc = bf2[k * OUT_F + o];
#pragma unroll
    for (int e = 0; e < 8; ++e)
      acc += hhs[k * 8 + e] * Wf2[(k * 8 + e) * OUT_F + o];
    const float p = 1.f / (1.f + __expf(-acc));
    out[(size_t)k * ngraphs * OUT_F + (size_t)g * OUT_F + o] = p;
  }
}

extern "C" void kernel_launch(void* const* d_in, const int* in_sizes, int n_in,
                              void* d_out, int out_size, void* d_ws, size_t ws_size,
                              hipStream_t stream) {
  const float* x      = (const float*)d_in[0];
  const float* y      = (const float*)d_in[1];
  // d_in[2] = edge_index, d_in[3] = batch : structure fixed, unused
  const float* W1     = (const float*)d_in[4];
  const float* a_src1 = (const float*)d_in[5];
  const float* a_dst1 = (const float*)d_in[6];
  const float* b1     = (const float*)d_in[7];
  const float* W2     = (const float*)d_in[8];
  const float* a_src2 = (const float*)d_in[9];
  const float* a_dst2 = (const float*)d_in[10];
  const float* b2     = (const float*)d_in[11];
  const float* Wf1    = (const float*)d_in[12];
  const float* bf1    = (const float*)d_in[13];
  const float* Wf2    = (const float*)d_in[14];
  const float* bf2    = (const float*)d_in[15];
  float* out = (float*)d_out;

  const int nnodes  = in_sizes[0] / IN_F;
  const int ngraphs = nnodes / NODES;

  hipLaunchKernelGGL(gnn_fused, dim3(ngraphs), dim3(64), 0, stream,
                     x, y, W1, a_src1, a_dst1, b1, W2, a_src2, a_dst2, b2,
                     Wf1, bf1, Wf2, bf2, out, ngraphs);
}